// Round 20
// baseline (109.079 us; speedup 1.0000x reference)
//
#include <hip/hip_runtime.h>
#include <stdint.h>
#include <math.h>

#define B_   2
#define S_   2048
#define D_   1024
#define H_   16
#define HD_  64
#define M_   (B_*S_)     // 4096
#define N3_  (3*D_)      // 3072

typedef __bf16 bf16;
typedef __bf16 bf16x2 __attribute__((ext_vector_type(2)));
typedef __bf16 bf16x4v __attribute__((ext_vector_type(4)));
typedef __bf16 bf16x8 __attribute__((ext_vector_type(8)));
typedef float  f32x4 __attribute__((ext_vector_type(4)));
typedef float  f32x16 __attribute__((ext_vector_type(16)));

__device__ __forceinline__ void gload_lds16(const void* g, void* l) {
  __builtin_amdgcn_global_load_lds(
      (__attribute__((address_space(1))) const unsigned int*)g,
      (__attribute__((address_space(3))) unsigned int*)l, 16, 0, 0);
}

// raw v_exp_f32 (2^x) via compiler builtin — P path only (proven r16)
__device__ __forceinline__ float fast_exp2(float x) {
  return __builtin_amdgcn_exp2f(x);
}

// ---------------- fused pre-pass: conv + both weight transposes + rope table ----------------
__global__ __launch_bounds__(256) void prep_kernel(const float* __restrict__ x, bf16* __restrict__ xb,
                                                   const float* __restrict__ w_qkv, bf16* __restrict__ wqkvT,
                                                   const float* __restrict__ w_proj, bf16* __restrict__ wprojT,
                                                   float* __restrict__ cosT, float* __restrict__ sinT) {
  __shared__ float tile[32][33];
  int blk = blockIdx.x, tid = threadIdx.x;
  if (blk < 1024) {
#pragma unroll
    for (int it = 0; it < 4; it++) {
      int i = (blk * 4 + it) * 256 + tid;
      float4 v = ((const float4*)x)[i];
      bf16x4v o;
      o[0] = (bf16)v.x; o[1] = (bf16)v.y; o[2] = (bf16)v.z; o[3] = (bf16)v.w;
      *(bf16x4v*)(xb + (size_t)i * 4) = o;
    }
  } else if (blk < 5120) {
    const float* in; bf16* out; int R, C, tb;
    if (blk < 4096) { in = w_qkv;  out = wqkvT;  R = 1024; C = 3072; tb = blk - 1024; }
    else            { in = w_proj; out = wprojT; R = 1024; C = 1024; tb = blk - 4096; }
    int nbx = C >> 5;
    int bx = tb % nbx, by = tb / nbx;
    int c0 = bx * 32, r0 = by * 32;
    int tx = tid & 31, ty = tid >> 5;
#pragma unroll
    for (int j = 0; j < 4; j++)
      tile[ty + j * 8][tx] = in[(size_t)(r0 + ty + j * 8) * C + c0 + tx];
    __syncthreads();
#pragma unroll
    for (int j = 0; j < 4; j++)
      out[(size_t)(c0 + ty + j * 8) * R + r0 + tx] = (bf16)tile[tx][ty + j * 8];
  } else {
    int i = (blk - 5120) * 256 + tid;
    int s = i >> 5, d = i & 31;
    float inv = powf(10000.0f, -(float)d * (1.0f / 32.0f));
    float a = (float)s * inv;
    float sv, cv;
    sincosf(a, &sv, &cv);
    cosT[i] = cv; sinT[i] = sv;
  }
}

// ---------------- qkv GEMM: BM=128, BN=192 (3 heads), BK=64; 512 blocks @ 2/CU ----------------
__global__ __launch_bounds__(512, 4) void gemm_qkv(const bf16* __restrict__ A,
                                                   const bf16* __restrict__ Bt,
                                                   bf16* __restrict__ Cb,
                                                   const float* __restrict__ cosT,
                                                   const float* __restrict__ sinT,
                                                   bf16* __restrict__ vt) {
  __shared__ __align__(16) unsigned char lds[81920];   // [2 buf][A 16K | B 24K]
  const int K = 1024;
  int tid = threadIdx.x, lane = tid & 63, w = tid >> 6;
  int bid = blockIdx.y * gridDim.x + blockIdx.x;       // nwg = 512
  int sw = (bid & 7) * 64 + (bid >> 3);
  int bx = sw & 15, by = sw >> 4;
  int m0 = by * 128, n0 = bx * 192;
  int rl = lane & 15, kg = lane >> 4;

  int r8 = tid >> 3;
  int cSw = ((tid & 7) ^ (r8 & 7)) * 16;
  const char* Ab = (const char*)A;
  const char* Bb = (const char*)Bt;

#define QSTG(kt, bf)                                                                        \
  do {                                                                                      \
    char* base = (char*)lds + (bf) * 40960;                                                 \
    _Pragma("unroll")                                                                       \
    for (int s = 0; s < 2; s++)                                                             \
      gload_lds16(Ab + ((size_t)(m0 + s * 64 + r8) * K + (kt) * 64) * 2 + cSw,              \
                  base + s * 8192 + tid * 16);                                              \
    _Pragma("unroll")                                                                       \
    for (int s = 0; s < 3; s++)                                                             \
      gload_lds16(Bb + ((size_t)(n0 + s * 64 + r8) * K + (kt) * 64) * 2 + cSw,              \
                  base + 16384 + s * 8192 + tid * 16);                                      \
  } while (0)

  int ch0 = ((kg + 0) ^ (rl & 7)) * 16;
  int ch1 = ((kg + 4) ^ (rl & 7)) * 16;
  int aoff = (w * 16 + rl) * 128;

  f32x4 acc[12] = {};

  QSTG(0, 0);
  asm volatile("s_waitcnt vmcnt(0)" ::: "memory");
  __builtin_amdgcn_s_barrier();

  for (int kt = 0; kt < 16; kt++) {
    int cur = kt & 1;
    if (kt + 1 < 16) QSTG(kt + 1, cur ^ 1);
    const char* base = (const char*)lds + cur * 40960;
    bf16x8 a0 = *(const bf16x8*)(base + aoff + ch0);
    bf16x8 a1 = *(const bf16x8*)(base + aoff + ch1);
    __builtin_amdgcn_s_setprio(1);
#pragma unroll
    for (int br = 0; br < 12; br++) {
      int boff = 16384 + (br * 16 + rl) * 128;
      bf16x8 b0 = *(const bf16x8*)(base + boff + ch0);
      bf16x8 b1 = *(const bf16x8*)(base + boff + ch1);
      acc[br] = __builtin_amdgcn_mfma_f32_16x16x32_bf16(a0, b0, acc[br], 0, 0, 0);
      acc[br] = __builtin_amdgcn_mfma_f32_16x16x32_bf16(a1, b1, acc[br], 0, 0, 0);
    }
    __builtin_amdgcn_s_setprio(0);
    asm volatile("s_waitcnt vmcnt(0)" ::: "memory");
    __builtin_amdgcn_s_barrier();
  }

  int rq = kg * 4;
#pragma unroll
  for (int hb = 0; hb < 3; hb++) {
    int g0 = n0 + hb * 64;
    if (g0 < 2048) {          // q/k: RoPE fused
#pragma unroll
      for (int j = 0; j < 2; j++) {
        int br = hb * 4 + j;
#pragma unroll
        for (int r = 0; r < 4; r++) {
          int row = m0 + w * 16 + rq + r;
          int srw = row & 2047;
          int d2 = j * 16 + rl;
          float c = cosT[srw * 32 + d2], sn = sinT[srw * 32 + d2];
          float x1 = acc[br][r], x2 = acc[br + 2][r];
          size_t o = (size_t)row * 3072 + g0 + d2;
          Cb[o]      = (bf16)(x1 * c - x2 * sn);
          Cb[o + 32] = (bf16)(x2 * c + x1 * sn);
        }
      }
    } else {                  // v: sigma-permuted V^T
      int posbase = ((rq & 4) << 1) | ((rq & 8) >> 1);
      int row0 = m0 + w * 16;
      int bb = row0 >> 11;
      int sbase = (row0 & 2047) + posbase;
#pragma unroll
      for (int j = 0; j < 4; j++) {
        int br = hb * 4 + j;
        int col = g0 + j * 16 + rl - 2048;
        bf16x4v pv;
        pv[0] = (bf16)acc[br][0]; pv[1] = (bf16)acc[br][1];
        pv[2] = (bf16)acc[br][2]; pv[3] = (bf16)acc[br][3];
        *(bf16x4v*)(vt + ((size_t)(bb * 1024 + col)) * 2048 + sbase) = pv;
      }
    }
  }
#undef QSTG
}

// ---------------- proj GEMM: BM=64, BN=128, BK=64 (swizzled), grid 512 ----------------
__global__ __launch_bounds__(256) void gemm_proj(const bf16* __restrict__ A,
                                                 const bf16* __restrict__ Bt,
                                                 float* __restrict__ Cf,
                                                 const float* __restrict__ bias) {
  __shared__ __align__(16) unsigned char As[8192];
  __shared__ __align__(16) unsigned char Bs[16384];
  const int K = 1024, N = 1024;
  int tid = threadIdx.x;
  int lane = tid & 63, w = tid >> 6;
  int bid = blockIdx.y * gridDim.x + blockIdx.x;
  int sw = (bid & 7) * 64 + (bid >> 3);
  int bx = sw & 7, by = sw >> 3;
  int m0 = by * 64, n0 = bx * 128;
  int m_off = (w >> 1) * 32, n_off = (w & 1) * 64;
  int rl = lane & 15, kg = lane >> 4;
  f32x4 acc[2][4] = {};

  const char* Ab = (const char*)A;
  const char* Bb = (const char*)Bt;
  int r8 = tid >> 3;
  int cSw = ((tid & 7) ^ (r8 & 7)) * 16;

  int ch0 = ((0 + kg) ^ (rl & 7)) * 16;
  int ch1 = ((4 + kg) ^ (rl & 7)) * 16;

  for (int k0 = 0; k0 < K; k0 += 64) {
#pragma unroll
    for (int s = 0; s < 2; s++) {
      int row = s * 32 + r8;
      gload_lds16(Ab + ((size_t)(m0 + row) * K + k0) * 2 + cSw, (char*)As + s * 4096 + tid * 16);
    }
#pragma unroll
    for (int s = 0; s < 4; s++) {
      int row = s * 32 + r8;
      gload_lds16(Bb + ((size_t)(n0 + row) * K + k0) * 2 + cSw, (char*)Bs + s * 4096 + tid * 16);
    }
    __syncthreads();
    bf16x8 a[2][2], b[4][2];
#pragma unroll
    for (int i = 0; i < 2; i++) {
      int row = m_off + i * 16 + rl;
      a[i][0] = *(const bf16x8*)((const char*)As + row * 128 + ch0);
      a[i][1] = *(const bf16x8*)((const char*)As + row * 128 + ch1);
    }
#pragma unroll
    for (int j = 0; j < 4; j++) {
      int row = n_off + j * 16 + rl;
      b[j][0] = *(const bf16x8*)((const char*)Bs + row * 128 + ch0);
      b[j][1] = *(const bf16x8*)((const char*)Bs + row * 128 + ch1);
    }
    __builtin_amdgcn_s_setprio(1);
#pragma unroll
    for (int i = 0; i < 2; i++)
#pragma unroll
      for (int j = 0; j < 4; j++) {
        acc[i][j] = __builtin_amdgcn_mfma_f32_16x16x32_bf16(a[i][0], b[j][0], acc[i][j], 0, 0, 0);
        acc[i][j] = __builtin_amdgcn_mfma_f32_16x16x32_bf16(a[i][1], b[j][1], acc[i][j], 0, 0, 0);
      }
    __builtin_amdgcn_s_setprio(0);
    __syncthreads();
  }

  int rq = kg * 4;
  for (int i = 0; i < 2; i++)
    for (int j = 0; j < 4; j++) {
      int col = n0 + n_off + j * 16 + rl;
      float bv = bias[col];
      for (int r = 0; r < 4; r++) {
        int row = m0 + m_off + i * 16 + rq + r;
        Cf[(size_t)row * N + col] = acc[i][j][r] + bv;
      }
    }
}

// ---------------- flash attention: 64-row q-tile, 4 kv-parities, 256-row KV chunks ----------------
// grid 1024 blocks x 512 threads; wave (qw,p): 32 q-rows, kv window i*256 + p*64.
__global__ __launch_bounds__(512, 2) void attn_kernel(const bf16* __restrict__ qkv,
                                                      const bf16* __restrict__ vt,
                                                      bf16* __restrict__ O) {
  __shared__ __align__(16) unsigned char smem[65536];  // K [256][64]b16 @0; V^T [64][256]b16 @32K; combine reuse
  int tid = threadIdx.x, lane = tid & 63, w = tid >> 6;
  int qw = w & 1, p = w >> 1;
  int bid = blockIdx.x;
  int u = bid >> 5;                        // 0..31
  int t64 = 31 - u;                        // LPT: heaviest first
  int jb = bid & 31;
  int bh = (jb & 7) * 4 + (jb >> 3);
  int b = bh >> 4, h = bh & 15;
  int q0w = t64 * 64 + qw * 32;
  int l31 = lane & 31, hi = lane >> 5;
  const char* qb = (const char*)qkv;
  const char* vb = (const char*)vt;

  // staging indices
  int l3 = lane >> 3;
  int kcS = ((lane & 7) ^ (l3 & 7)) * 16;          // K: 8-chunk rows, swz by row&7
  int d5 = lane >> 5;                               // V: d offset within wave's 2 rows

  // Q fragments (B-operand), scale = 1/8 * log2(e) folded
  bf16x8 aq[4];
#pragma unroll
  for (int s = 0; s < 4; s++) {
    size_t row = (size_t)(b * 2048 + q0w + l31);
    bf16x8 v = *(const bf16x8*)(qb + (row * 3072 + h * 64 + s * 16 + hi * 8) * 2);
#pragma unroll
    for (int e = 0; e < 8; e++) v[e] = (bf16)((float)v[e] * 0.18033688f);
    aq[s] = v;
  }

  f32x16 o0 = {}, o1 = {};
  float mrun = -3e38f, lrun = 0.f;
  int npair = t64 / 4 + 1;

  for (int i = 0; i < npair; i++) {
    int kv0 = i * 256;
    // ---- stage K [256][64] and V^T [64][256] (single buffer) ----
#pragma unroll
    for (int s = 0; s < 4; s++) {
      int row = s * 64 + w * 8 + l3;
      gload_lds16(qb + (((size_t)(b * 2048 + kv0 + row) * 3072) + 1024 + h * 64) * 2 + kcS,
                  (char*)smem + (s * 64 + w * 8) * 128 + lane * 16);
    }
#pragma unroll
    for (int s = 0; s < 4; s++) {
      int d = s * 16 + w * 2 + d5;
      int vch = ((lane & 31) ^ (d & 7)) * 16;
      gload_lds16(vb + (((size_t)(bh * 64 + d) * 2048) + kv0) * 2 + vch,
                  (char*)smem + 32768 + (s * 16 + w * 2) * 512 + lane * 16);
    }
    asm volatile("s_waitcnt vmcnt(0)" ::: "memory");
    __builtin_amdgcn_s_barrier();

    int kvw = kv0 + p * 64;
    if (kvw <= q0w + 31) {
      bool diag = (kvw + 63 > q0w);

      f32x16 scr[2];
#pragma unroll
      for (int kf = 0; kf < 2; kf++)
#pragma unroll
        for (int r = 0; r < 16; r++) scr[kf][r] = 0.f;
      __builtin_amdgcn_s_setprio(1);
#pragma unroll
      for (int s = 0; s < 4; s++) {
#pragma unroll
        for (int kf = 0; kf < 2; kf++) {
          int row = p * 64 + kf * 32 + l31;
          int ch = (hi + 2 * s) ^ (l31 & 7);
          bf16x8 ak = *(const bf16x8*)((const char*)smem + row * 128 + ch * 16);
          scr[kf] = __builtin_amdgcn_mfma_f32_32x32x16_bf16(ak, aq[s], scr[kf], 0, 0, 0);
        }
      }
      __builtin_amdgcn_s_setprio(0);

      int qg = q0w + l31;
      if (diag) {
#pragma unroll
        for (int kf = 0; kf < 2; kf++)
#pragma unroll
          for (int r = 0; r < 16; r++) {
            int k = kvw + kf * 32 + (r & 3) + 8 * (r >> 2) + 4 * hi;
            if (k > qg) scr[kf][r] = -3e38f;
          }
      }

      float mx = -3e38f;
#pragma unroll
      for (int kf = 0; kf < 2; kf++)
#pragma unroll
        for (int r = 0; r < 16; r++) mx = fmaxf(mx, scr[kf][r]);
      mx = fmaxf(mx, __shfl_xor(mx, 32));

      // T13 defer-max
      if (!__all(mx - mrun <= 11.5f)) {
        float mnew = fmaxf(mrun, mx);
        float corr = exp2f(mrun - mnew);
        mrun = mnew;
        lrun *= corr;
#pragma unroll
        for (int r = 0; r < 16; r++) {
          float cr = __shfl(corr, (r & 3) + 8 * (r >> 2) + 4 * hi);
          o0[r] *= cr; o1[r] *= cr;
        }
      }

      float rs = 0.f;
      unsigned D[2][8];
#pragma unroll
      for (int kf = 0; kf < 2; kf++)
#pragma unroll
        for (int j = 0; j < 8; j++) {
          float p0 = fast_exp2(scr[kf][2 * j] - mrun);
          float p1 = fast_exp2(scr[kf][2 * j + 1] - mrun);
          rs += p0 + p1;
          bf16x2 tp; tp[0] = (bf16)p0; tp[1] = (bf16)p1;
          D[kf][j] = __builtin_bit_cast(unsigned, tp);
        }
      rs += __shfl_xor(rs, 32);
      lrun += rs;

#pragma unroll
      for (int kf = 0; kf < 2; kf++) {
#pragma unroll
        for (int sg = 0; sg < 2; sg++) {
          union { unsigned u4[4]; bf16x8 v; } ap;
          ap.u4[0] = D[kf][4 * sg + 0];
          ap.u4[1] = D[kf][4 * sg + 1];
          ap.u4[2] = D[kf][4 * sg + 2];
          ap.u4[3] = D[kf][4 * sg + 3];
          __builtin_amdgcn_s_setprio(1);
#pragma unroll
          for (int nf = 0; nf < 2; nf++) {
            int d = nf * 32 + l31;
            int ch = p * 8 + ((hi + 2 * sg + 4 * kf) ^ (d & 7));
            bf16x8 bv = *(const bf16x8*)((const char*)smem + 32768 + d * 512 + ch * 16);
            if (nf == 0) o0 = __builtin_amdgcn_mfma_f32_32x32x16_bf16(ap.v, bv, o0, 0, 0, 0);
            else         o1 = __builtin_amdgcn_mfma_f32_32x32x16_bf16(ap.v, bv, o1, 0, 0, 0);
          }
          __builtin_amdgcn_s_setprio(0);
        }
      }
    }
    __builtin_amdgcn_s_barrier();   // all reads done before next stage overwrites
  }

  // ---- 4-way cross-parity combine (reuse smem) ----
  float* mlb  = (float*)(smem + 63488);   // 8 slots x 64 floats (m at l31, l at 32+l31)
  float* obuf = (float*)smem;             // 6 slots x 2048 floats (p=1..3 scaled partials)
  if (hi == 0) {
    mlb[(qw * 4 + p) * 64 + l31]      = mrun;
    mlb[(qw * 4 + p) * 64 + 32 + l31] = lrun;
  }
  __syncthreads();
  float mj[4], lj[4];
#pragma unroll
  for (int j = 0; j < 4; j++) {
    mj[j] = mlb[(qw * 4 + j) * 64 + l31];
    lj[j] = mlb[(qw * 4 + j) * 64 + 32 + l31];
  }
  float M = fmaxf(fmaxf(mj[0], mj[1]), fmaxf(mj[2], mj[3]));
  float L = lj[0] * exp2f(mj[0] - M) + lj[1] * exp2f(mj[1] - M)
          + lj[2] * exp2f(mj[2] - M) + lj[3] * exp2f(mj[3] - M);
  float Smine = exp2f(mrun - M);
  float Li = 1.0f / L;
  if (p != 0) {
    int slot = qw * 3 + (p - 1);
#pragma unroll
    for (int r = 0; r < 16; r++) {
      int crow = (r & 3) + 8 * (r >> 2) + 4 * hi;
      float sc = __shfl(Smine, crow);
      obuf[slot * 2048 + crow * 64 + l31]      = o0[r] * sc;
      obuf[slot * 2048 + crow * 64 + 32 + l31] = o1[r] * sc;
    }
  }
  __syncthreads();
  if (p == 0) {
#pragma unroll
    for (int r = 0; r < 16; r++) {
      int crow = (r & 3) + 8 * (r >> 2) + 4 * hi;
      float sc = __shfl(Smine, crow);
      float li = __shfl(Li, crow);
      float v0 = o0[r] * sc, v1 = o1[r] * sc;
#pragma unroll
      for (int j = 0; j < 3; j++) {
        int slot = qw * 3 + j;
        v0 += obuf[slot * 2048 + crow * 64 + l31];
        v1 += obuf[slot * 2048 + crow * 64 + 32 + l31];
      }
      size_t row = (size_t)(b * 2048 + q0w + crow);
      O[row * 1024 + h * 64 + l31]      = (bf16)(v0 * li);
      O[row * 1024 + h * 64 + 32 + l31] = (bf16)(v1 * li);
    }
  }
}

extern "C" void kernel_launch(void* const* d_in, const int* in_sizes, int n_in,
                              void* d_out, int out_size, void* d_ws, size_t ws_size,
                              hipStream_t stream) {
  const float* x      = (const float*)d_in[0];
  const float* w_qkv  = (const float*)d_in[1];
  const float* w_proj = (const float*)d_in[2];
  const float* b_proj = (const float*)d_in[3];

  char* ws = (char*)d_ws;
  size_t off = 0;
  bf16* xb     = (bf16*)(ws + off); off += (size_t)M_ * D_ * 2;
  bf16* wqkvT  = (bf16*)(ws + off); off += (size_t)N3_ * D_ * 2;
  bf16* wprojT = (bf16*)(ws + off); off += (size_t)D_ * D_ * 2;
  bf16* qkvb   = (bf16*)(ws + off); off += (size_t)M_ * N3_ * 2;
  bf16* ob     = (bf16*)(ws + off); off += (size_t)M_ * D_ * 2;
  bf16* vtb    = (bf16*)(ws + off); off += (size_t)M_ * D_ * 2;
  float* cosT  = (float*)(ws + off); off += (size_t)S_ * 32 * 4;
  float* sinT  = (float*)(ws + off); off += (size_t)S_ * 32 * 4;

  prep_kernel<<<5376, 256, 0, stream>>>(x, xb, w_qkv, wqkvT, w_proj, wprojT, cosT, sinT);
  gemm_qkv<<<dim3(16, 32), 512, 0, stream>>>(xb, wqkvT, qkvb, cosT, sinT, vtb);
  attn_kernel<<<1024, 512, 0, stream>>>(qkvb, vtb, ob);
  gemm_proj<<<dim3(8, 64), 256, 0, stream>>>(ob, wprojT, (float*)d_out, b_proj);
}

// Round 21
// 96.736 us; speedup vs baseline: 1.1276x; 1.1276x over previous
//
#include <hip/hip_runtime.h>
#include <stdint.h>
#include <math.h>

#define B_   2
#define S_   2048
#define D_   1024
#define H_   16
#define HD_  64
#define M_   (B_*S_)     // 4096
#define N3_  (3*D_)      // 3072

typedef __bf16 bf16;
typedef __bf16 bf16x2 __attribute__((ext_vector_type(2)));
typedef __bf16 bf16x4v __attribute__((ext_vector_type(4)));
typedef __bf16 bf16x8 __attribute__((ext_vector_type(8)));
typedef float  f32x4 __attribute__((ext_vector_type(4)));
typedef float  f32x16 __attribute__((ext_vector_type(16)));

__device__ __forceinline__ void gload_lds16(const void* g, void* l) {
  __builtin_amdgcn_global_load_lds(
      (__attribute__((address_space(1))) const unsigned int*)g,
      (__attribute__((address_space(3))) unsigned int*)l, 16, 0, 0);
}

// raw v_exp_f32 (2^x) via compiler builtin — P path only (proven r16)
__device__ __forceinline__ float fast_exp2(float x) {
  return __builtin_amdgcn_exp2f(x);
}

// ---------------- fused pre-pass: conv + both weight transposes + rope table ----------------
__global__ __launch_bounds__(256) void prep_kernel(const float* __restrict__ x, bf16* __restrict__ xb,
                                                   const float* __restrict__ w_qkv, bf16* __restrict__ wqkvT,
                                                   const float* __restrict__ w_proj, bf16* __restrict__ wprojT,
                                                   float* __restrict__ cosT, float* __restrict__ sinT) {
  __shared__ float tile[32][33];
  int blk = blockIdx.x, tid = threadIdx.x;
  if (blk < 1024) {
#pragma unroll
    for (int it = 0; it < 4; it++) {
      int i = (blk * 4 + it) * 256 + tid;
      float4 v = ((const float4*)x)[i];
      bf16x4v o;
      o[0] = (bf16)v.x; o[1] = (bf16)v.y; o[2] = (bf16)v.z; o[3] = (bf16)v.w;
      *(bf16x4v*)(xb + (size_t)i * 4) = o;
    }
  } else if (blk < 5120) {
    const float* in; bf16* out; int R, C, tb;
    if (blk < 4096) { in = w_qkv;  out = wqkvT;  R = 1024; C = 3072; tb = blk - 1024; }
    else            { in = w_proj; out = wprojT; R = 1024; C = 1024; tb = blk - 4096; }
    int nbx = C >> 5;
    int bx = tb % nbx, by = tb / nbx;
    int c0 = bx * 32, r0 = by * 32;
    int tx = tid & 31, ty = tid >> 5;
#pragma unroll
    for (int j = 0; j < 4; j++)
      tile[ty + j * 8][tx] = in[(size_t)(r0 + ty + j * 8) * C + c0 + tx];
    __syncthreads();
#pragma unroll
    for (int j = 0; j < 4; j++)
      out[(size_t)(c0 + ty + j * 8) * R + r0 + tx] = (bf16)tile[tx][ty + j * 8];
  } else {
    int i = (blk - 5120) * 256 + tid;
    int s = i >> 5, d = i & 31;
    float inv = powf(10000.0f, -(float)d * (1.0f / 32.0f));
    float a = (float)s * inv;
    float sv, cv;
    sincosf(a, &sv, &cv);
    cosT[i] = cv; sinT[i] = sv;
  }
}

// ---------------- qkv GEMM: BM=128, BN=192 (3 heads), BK=64; 512 blocks @ 2/CU ----------------
// 8 waves, wave w owns rows w*16..w*16+15 x all 192 cols (acc[12], RoPE pairs intra-wave).
__global__ __launch_bounds__(512, 4) void gemm_qkv(const bf16* __restrict__ A,
                                                   const bf16* __restrict__ Bt,
                                                   bf16* __restrict__ Cb,
                                                   const float* __restrict__ cosT,
                                                   const float* __restrict__ sinT,
                                                   bf16* __restrict__ vt) {
  __shared__ __align__(16) unsigned char lds[81920];   // [2 buf][A 16K | B 24K]
  const int K = 1024;
  int tid = threadIdx.x, lane = tid & 63, w = tid >> 6;
  int bid = blockIdx.y * gridDim.x + blockIdx.x;       // nwg = 512
  int sw = (bid & 7) * 64 + (bid >> 3);
  int bx = sw & 15, by = sw >> 4;
  int m0 = by * 128, n0 = bx * 192;
  int rl = lane & 15, kg = lane >> 4;

  // staging: 512 threads; r8 = tid>>3 covers 64 rows/shot, chunk c8 = tid&7 (128B rows)
  int r8 = tid >> 3;
  int cSw = ((tid & 7) ^ (r8 & 7)) * 16;               // pre-swizzled source chunk (involution)
  const char* Ab = (const char*)A;
  const char* Bb = (const char*)Bt;

#define QSTG(kt, bf)                                                                        \
  do {                                                                                      \
    char* base = (char*)lds + (bf) * 40960;                                                 \
    _Pragma("unroll")                                                                       \
    for (int s = 0; s < 2; s++)                                                             \
      gload_lds16(Ab + ((size_t)(m0 + s * 64 + r8) * K + (kt) * 64) * 2 + cSw,              \
                  base + s * 8192 + tid * 16);                                              \
    _Pragma("unroll")                                                                       \
    for (int s = 0; s < 3; s++)                                                             \
      gload_lds16(Bb + ((size_t)(n0 + s * 64 + r8) * K + (kt) * 64) * 2 + cSw,              \
                  base + 16384 + s * 8192 + tid * 16);                                      \
  } while (0)

  // read offsets: A row = w*16 + rl; chunk(ks) = (kg + 4*ks) ^ (rl & 7)
  int ch0 = ((kg + 0) ^ (rl & 7)) * 16;
  int ch1 = ((kg + 4) ^ (rl & 7)) * 16;
  int aoff = (w * 16 + rl) * 128;

  f32x4 acc[12] = {};

  QSTG(0, 0);
  asm volatile("s_waitcnt vmcnt(0)" ::: "memory");
  __builtin_amdgcn_s_barrier();

  for (int kt = 0; kt < 16; kt++) {
    int cur = kt & 1;
    if (kt + 1 < 16) QSTG(kt + 1, cur ^ 1);
    const char* base = (const char*)lds + cur * 40960;
    bf16x8 a0 = *(const bf16x8*)(base + aoff + ch0);
    bf16x8 a1 = *(const bf16x8*)(base + aoff + ch1);
    __builtin_amdgcn_s_setprio(1);
#pragma unroll
    for (int br = 0; br < 12; br++) {
      int boff = 16384 + (br * 16 + rl) * 128;
      bf16x8 b0 = *(const bf16x8*)(base + boff + ch0);
      bf16x8 b1 = *(const bf16x8*)(base + boff + ch1);
      acc[br] = __builtin_amdgcn_mfma_f32_16x16x32_bf16(a0, b0, acc[br], 0, 0, 0);
      acc[br] = __builtin_amdgcn_mfma_f32_16x16x32_bf16(a1, b1, acc[br], 0, 0, 0);
    }
    __builtin_amdgcn_s_setprio(0);
    asm volatile("s_waitcnt vmcnt(0)" ::: "memory");
    __builtin_amdgcn_s_barrier();
  }

  // ---- epilogue: per-64-col head group (n0 is 64-aligned) ----
  int rq = kg * 4;
#pragma unroll
  for (int hb = 0; hb < 3; hb++) {
    int g0 = n0 + hb * 64;
    if (g0 < 2048) {          // q/k: RoPE fused
#pragma unroll
      for (int j = 0; j < 2; j++) {
        int br = hb * 4 + j;
#pragma unroll
        for (int r = 0; r < 4; r++) {
          int row = m0 + w * 16 + rq + r;
          int srw = row & 2047;
          int d2 = j * 16 + rl;
          float c = cosT[srw * 32 + d2], sn = sinT[srw * 32 + d2];
          float x1 = acc[br][r], x2 = acc[br + 2][r];
          size_t o = (size_t)row * 3072 + g0 + d2;
          Cb[o]      = (bf16)(x1 * c - x2 * sn);
          Cb[o + 32] = (bf16)(x2 * c + x1 * sn);
        }
      }
    } else {                  // v: sigma-permuted V^T
      int posbase = ((rq & 4) << 1) | ((rq & 8) >> 1);
      int row0 = m0 + w * 16;                 // 16-aligned
      int bb = row0 >> 11;
      int sbase = (row0 & 2047) + posbase;
#pragma unroll
      for (int j = 0; j < 4; j++) {
        int br = hb * 4 + j;
        int col = g0 + j * 16 + rl - 2048;
        bf16x4v pv;
        pv[0] = (bf16)acc[br][0]; pv[1] = (bf16)acc[br][1];
        pv[2] = (bf16)acc[br][2]; pv[3] = (bf16)acc[br][3];
        *(bf16x4v*)(vt + ((size_t)(bb * 1024 + col)) * 2048 + sbase) = pv;
      }
    }
  }
#undef QSTG
}

// ---------------- proj GEMM: BM=64, BN=128, BK=64 (swizzled), grid 512 ----------------
__global__ __launch_bounds__(256) void gemm_proj(const bf16* __restrict__ A,
                                                 const bf16* __restrict__ Bt,
                                                 float* __restrict__ Cf,
                                                 const float* __restrict__ bias) {
  __shared__ __align__(16) unsigned char As[8192];    // [64][64] bf16, 128B rows
  __shared__ __align__(16) unsigned char Bs[16384];   // [128][64] bf16
  const int K = 1024, N = 1024;
  int tid = threadIdx.x;
  int lane = tid & 63, w = tid >> 6;
  int bid = blockIdx.y * gridDim.x + blockIdx.x;   // nwg = 512
  int sw = (bid & 7) * 64 + (bid >> 3);
  int bx = sw & 7, by = sw >> 3;
  int m0 = by * 64, n0 = bx * 128;
  int m_off = (w >> 1) * 32, n_off = (w & 1) * 64;
  int rl = lane & 15, kg = lane >> 4;
  f32x4 acc[2][4] = {};

  const char* Ab = (const char*)A;
  const char* Bb = (const char*)Bt;
  int r8 = tid >> 3;
  int cSw = ((tid & 7) ^ (r8 & 7)) * 16;

  int ch0 = ((0 + kg) ^ (rl & 7)) * 16;
  int ch1 = ((4 + kg) ^ (rl & 7)) * 16;

  for (int k0 = 0; k0 < K; k0 += 64) {
#pragma unroll
    for (int s = 0; s < 2; s++) {
      int row = s * 32 + r8;
      gload_lds16(Ab + ((size_t)(m0 + row) * K + k0) * 2 + cSw, (char*)As + s * 4096 + tid * 16);
    }
#pragma unroll
    for (int s = 0; s < 4; s++) {
      int row = s * 32 + r8;
      gload_lds16(Bb + ((size_t)(n0 + row) * K + k0) * 2 + cSw, (char*)Bs + s * 4096 + tid * 16);
    }
    __syncthreads();
    bf16x8 a[2][2], b[4][2];
#pragma unroll
    for (int i = 0; i < 2; i++) {
      int row = m_off + i * 16 + rl;
      a[i][0] = *(const bf16x8*)((const char*)As + row * 128 + ch0);
      a[i][1] = *(const bf16x8*)((const char*)As + row * 128 + ch1);
    }
#pragma unroll
    for (int j = 0; j < 4; j++) {
      int row = n_off + j * 16 + rl;
      b[j][0] = *(const bf16x8*)((const char*)Bs + row * 128 + ch0);
      b[j][1] = *(const bf16x8*)((const char*)Bs + row * 128 + ch1);
    }
    __builtin_amdgcn_s_setprio(1);
#pragma unroll
    for (int i = 0; i < 2; i++)
#pragma unroll
      for (int j = 0; j < 4; j++) {
        acc[i][j] = __builtin_amdgcn_mfma_f32_16x16x32_bf16(a[i][0], b[j][0], acc[i][j], 0, 0, 0);
        acc[i][j] = __builtin_amdgcn_mfma_f32_16x16x32_bf16(a[i][1], b[j][1], acc[i][j], 0, 0, 0);
      }
    __builtin_amdgcn_s_setprio(0);
    __syncthreads();
  }

  int rq = kg * 4;
  for (int i = 0; i < 2; i++)
    for (int j = 0; j < 4; j++) {
      int col = n0 + n_off + j * 16 + rl;
      float bv = bias[col];
      for (int r = 0; r < 4; r++) {
        int row = m0 + m_off + i * 16 + rq + r;
        Cf[(size_t)row * N + col] = acc[i][j][r] + bv;
      }
    }
}

// ---------------- flash attention: r16-exact (LPT, setprio, raw-exp P path) ----------------
__global__ __launch_bounds__(512, 4) void attn_kernel(const bf16* __restrict__ qkv,
                                                      const bf16* __restrict__ vt,
                                                      bf16* __restrict__ O) {
  __shared__ __align__(16) unsigned char Ks[2][16384];
  __shared__ __align__(16) unsigned char Vs[2][16384];
  int tid = threadIdx.x, lane = tid & 63, w = tid >> 6;
  int qw = w & 3, p = w >> 2;
  int bid = blockIdx.x;
  int xcd = bid & 7, slot = bid >> 3;
  int bh = xcd * 4 + (slot & 3);
  int u = slot >> 2;
  int qt = 15 - u;                         // LPT
  int b = bh >> 4, h = bh & 15;
  int q0w = qt * 128 + qw * 32;
  int l31 = lane & 31, hi = lane >> 5;
  const char* qb = (const char*)qkv;
  const char* vb = (const char*)vt;

  int kr0 = tid >> 3, kcs = (tid & 7) ^ (kr0 & 7);
  int vr0 = tid >> 4, vcs = (tid & 15) ^ (vr0 & 7);

#define STAGE(buf, kvbase)                                                                              \
  do {                                                                                                  \
    gload_lds16(qb + (((size_t)(b * 2048 + (kvbase) + kr0) * 3072) + 1024 + h * 64) * 2 + kcs * 16,     \
                (char*)Ks[buf] + tid * 16);                                                             \
    gload_lds16(qb + (((size_t)(b * 2048 + (kvbase) + kr0 + 64) * 3072) + 1024 + h * 64) * 2 + kcs * 16,\
                (char*)Ks[buf] + (tid + 512) * 16);                                                     \
    gload_lds16(vb + (((size_t)(bh * 64 + vr0) * 2048) + (kvbase)) * 2 + vcs * 16,                      \
                (char*)Vs[buf] + tid * 16);                                                             \
    gload_lds16(vb + (((size_t)(bh * 64 + vr0 + 32) * 2048) + (kvbase)) * 2 + vcs * 16,                 \
                (char*)Vs[buf] + (tid + 512) * 16);                                                     \
  } while (0)

  bf16x8 aq[4];
#pragma unroll
  for (int s = 0; s < 4; s++) {
    size_t row = (size_t)(b * 2048 + q0w + l31);
    bf16x8 v = *(const bf16x8*)(qb + (row * 3072 + h * 64 + s * 16 + hi * 8) * 2);
#pragma unroll
    for (int e = 0; e < 8; e++) v[e] = (bf16)((float)v[e] * 0.18033688f);
    aq[s] = v;
  }

  f32x16 o0 = {}, o1 = {};
  float mrun = -3e38f, lrun = 0.f;
  int npair = qt + 1;

  STAGE(0, 0);
  asm volatile("s_waitcnt vmcnt(0)" ::: "memory");
  __builtin_amdgcn_s_barrier();

  for (int i = 0; i < npair; i++) {
    int cur = i & 1;
    if (i + 1 < npair) STAGE(cur ^ 1, (i + 1) * 128);

    int kvw = i * 128 + p * 64;
    if (kvw <= q0w + 31) {
      bool diag = (kvw + 63 > q0w);

      f32x16 scr[2];
#pragma unroll
      for (int kf = 0; kf < 2; kf++)
#pragma unroll
        for (int r = 0; r < 16; r++) scr[kf][r] = 0.f;
      __builtin_amdgcn_s_setprio(1);
#pragma unroll
      for (int s = 0; s < 4; s++) {
#pragma unroll
        for (int kf = 0; kf < 2; kf++) {
          int row = p * 64 + kf * 32 + l31;
          int ch = (hi + 2 * s) ^ (row & 7);
          bf16x8 ak = *(const bf16x8*)(Ks[cur] + row * 128 + ch * 16);
          scr[kf] = __builtin_amdgcn_mfma_f32_32x32x16_bf16(ak, aq[s], scr[kf], 0, 0, 0);
        }
      }
      __builtin_amdgcn_s_setprio(0);

      int qg = q0w + l31;
      if (diag) {
#pragma unroll
        for (int kf = 0; kf < 2; kf++)
#pragma unroll
          for (int r = 0; r < 16; r++) {
            int k = kvw + kf * 32 + (r & 3) + 8 * (r >> 2) + 4 * hi;
            if (k > qg) scr[kf][r] = -3e38f;
          }
      }

      float mx = -3e38f;
#pragma unroll
      for (int kf = 0; kf < 2; kf++)
#pragma unroll
        for (int r = 0; r < 16; r++) mx = fmaxf(mx, scr[kf][r]);
      mx = fmaxf(mx, __shfl_xor(mx, 32));

      // T13 defer-max (state path libm exp2f)
      if (!__all(mx - mrun <= 11.5f)) {
        float mnew = fmaxf(mrun, mx);
        float corr = exp2f(mrun - mnew);
        mrun = mnew;
        lrun *= corr;
#pragma unroll
        for (int r = 0; r < 16; r++) {
          float cr = __shfl(corr, (r & 3) + 8 * (r >> 2) + 4 * hi);
          o0[r] *= cr; o1[r] *= cr;
        }
      }

      float rs = 0.f;
      unsigned D[2][8];
#pragma unroll
      for (int kf = 0; kf < 2; kf++)
#pragma unroll
        for (int j = 0; j < 8; j++) {
          float p0 = fast_exp2(scr[kf][2 * j] - mrun);
          float p1 = fast_exp2(scr[kf][2 * j + 1] - mrun);
          rs += p0 + p1;
          bf16x2 tp; tp[0] = (bf16)p0; tp[1] = (bf16)p1;
          D[kf][j] = __builtin_bit_cast(unsigned, tp);
        }
      rs += __shfl_xor(rs, 32);
      lrun += rs;

#pragma unroll
      for (int kf = 0; kf < 2; kf++) {
#pragma unroll
        for (int sg = 0; sg < 2; sg++) {
          union { unsigned u4[4]; bf16x8 v; } ap;
          ap.u4[0] = D[kf][4 * sg + 0];
          ap.u4[1] = D[kf][4 * sg + 1];
          ap.u4[2] = D[kf][4 * sg + 2];
          ap.u4[3] = D[kf][4 * sg + 3];
          __builtin_amdgcn_s_setprio(1);
#pragma unroll
          for (int nf = 0; nf < 2; nf++) {
            int row = nf * 32 + l31;
            int ch = ((p * 8) + (hi + 2 * sg + 4 * kf)) ^ (row & 7);
            bf16x8 bv = *(const bf16x8*)(Vs[cur] + row * 256 + ch * 16);
            if (nf == 0) o0 = __builtin_amdgcn_mfma_f32_32x32x16_bf16(ap.v, bv, o0, 0, 0, 0);
            else         o1 = __builtin_amdgcn_mfma_f32_32x32x16_bf16(ap.v, bv, o1, 0, 0, 0);
          }
          __builtin_amdgcn_s_setprio(0);
        }
      }
    }

    asm volatile("s_waitcnt vmcnt(0)" ::: "memory");
    __builtin_amdgcn_s_barrier();
  }

  float* mlb = (float*)Ks;
  if (hi == 0) {
    mlb[((qw * 2 + p) * 2 + 0) * 32 + l31] = mrun;
    mlb[((qw * 2 + p) * 2 + 1) * 32 + l31] = lrun;
  }
  __syncthreads();
  float m_o = mlb[((qw * 2 + (1 - p)) * 2 + 0) * 32 + l31];
  float l_o = mlb[((qw * 2 + (1 - p)) * 2 + 1) * 32 + l31];
  float Mm = fmaxf(mrun, m_o);
  float cs = exp2f(mrun - Mm);
  float L  = lrun * cs + l_o * exp2f(m_o - Mm);
  float* obuf = (float*)Vs;
  if (p == 1) {
#pragma unroll
    for (int r = 0; r < 16; r++) {
      int crow = (r & 3) + 8 * (r >> 2) + 4 * hi;
      float c = __shfl(cs, crow);
      obuf[qw * 2048 + r * 64 + lane]        = o0[r] * c;
      obuf[qw * 2048 + (r + 16) * 64 + lane] = o1[r] * c;
    }
  }
  __syncthreads();
  if (p == 0) {
    float linv = 1.0f / L;
#pragma unroll
    for (int r = 0; r < 16; r++) {
      int crow = (r & 3) + 8 * (r >> 2) + 4 * hi;
      float c  = __shfl(cs, crow);
      float li = __shfl(linv, crow);
      size_t row = (size_t)(b * 2048 + q0w + crow);
      float v0 = (o0[r] * c + obuf[qw * 2048 + r * 64 + lane]) * li;
      float v1 = (o1[r] * c + obuf[qw * 2048 + (r + 16) * 64 + lane]) * li;
      O[row * 1024 + h * 64 + l31]      = (bf16)v0;
      O[row * 1024 + h * 64 + 32 + l31] = (bf16)v1;
    }
  }
#undef STAGE
}

extern "C" void kernel_launch(void* const* d_in, const int* in_sizes, int n_in,
                              void* d_out, int out_size, void* d_ws, size_t ws_size,
                              hipStream_t stream) {
  const float* x      = (const float*)d_in[0];
  const float* w_qkv  = (const float*)d_in[1];
  const float* w_proj = (const float*)d_in[2];
  const float* b_proj = (const float*)d_in[3];

  char* ws = (char*)d_ws;
  size_t off = 0;
  bf16* xb     = (bf16*)(ws + off); off += (size_t)M_ * D_ * 2;
  bf16* wqkvT  = (bf16*)(ws + off); off += (size_t)N3_ * D_ * 2;
  bf16* wprojT = (bf16*)(ws + off); off += (size_t)D_ * D_ * 2;
  bf16* qkvb   = (bf16*)(ws + off); off += (size_t)M_ * N3_ * 2;
  bf16* ob     = (bf16*)(ws + off); off += (size_t)M_ * D_ * 2;
  bf16* vtb    = (bf16*)(ws + off); off += (size_t)M_ * D_ * 2;
  float* cosT  = (float*)(ws + off); off += (size_t)S_ * 32 * 4;
  float* sinT  = (float*)(ws + off); off += (size_t)S_ * 32 * 4;

  prep_kernel<<<5376, 256, 0, stream>>>(x, xb, w_qkv, wqkvT, w_proj, wprojT, cosT, sinT);
  gemm_qkv<<<dim3(16, 32), 512, 0, stream>>>(xb, wqkvT, qkvb, cosT, sinT, vtb);
  attn_kernel<<<512, 512, 0, stream>>>(qkvb, vtb, ob);
  gemm_proj<<<dim3(8, 64), 256, 0, stream>>>(ob, wprojT, (float*)d_out, b_proj);
}

// Round 22
// 92.338 us; speedup vs baseline: 1.1813x; 1.0476x over previous
//
#include <hip/hip_runtime.h>
#include <stdint.h>
#include <math.h>

#define B_   2
#define S_   2048
#define D_   1024
#define H_   16
#define HD_  64
#define M_   (B_*S_)     // 4096
#define N3_  (3*D_)      // 3072

typedef __bf16 bf16;
typedef __bf16 bf16x2 __attribute__((ext_vector_type(2)));
typedef __bf16 bf16x4v __attribute__((ext_vector_type(4)));
typedef __bf16 bf16x8 __attribute__((ext_vector_type(8)));
typedef float  f32x4 __attribute__((ext_vector_type(4)));
typedef float  f32x16 __attribute__((ext_vector_type(16)));

__device__ __forceinline__ void gload_lds16(const void* g, void* l) {
  __builtin_amdgcn_global_load_lds(
      (__attribute__((address_space(1))) const unsigned int*)g,
      (__attribute__((address_space(3))) unsigned int*)l, 16, 0, 0);
}

// raw v_exp_f32 (2^x) via compiler builtin — P path only (proven r16)
__device__ __forceinline__ float fast_exp2(float x) {
  return __builtin_amdgcn_exp2f(x);
}

// ---------------- fused pre-pass: conv + both weight transposes + rope table ----------------
__global__ __launch_bounds__(256) void prep_kernel(const float* __restrict__ x, bf16* __restrict__ xb,
                                                   const float* __restrict__ w_qkv, bf16* __restrict__ wqkvT,
                                                   const float* __restrict__ w_proj, bf16* __restrict__ wprojT,
                                                   float* __restrict__ cosT, float* __restrict__ sinT) {
  __shared__ float tile[32][33];
  int blk = blockIdx.x, tid = threadIdx.x;
  if (blk < 1024) {
#pragma unroll
    for (int it = 0; it < 4; it++) {
      int i = (blk * 4 + it) * 256 + tid;
      float4 v = ((const float4*)x)[i];
      bf16x4v o;
      o[0] = (bf16)v.x; o[1] = (bf16)v.y; o[2] = (bf16)v.z; o[3] = (bf16)v.w;
      *(bf16x4v*)(xb + (size_t)i * 4) = o;
    }
  } else if (blk < 5120) {
    const float* in; bf16* out; int R, C, tb;
    if (blk < 4096) { in = w_qkv;  out = wqkvT;  R = 1024; C = 3072; tb = blk - 1024; }
    else            { in = w_proj; out = wprojT; R = 1024; C = 1024; tb = blk - 4096; }
    int nbx = C >> 5;
    int bx = tb % nbx, by = tb / nbx;
    int c0 = bx * 32, r0 = by * 32;
    int tx = tid & 31, ty = tid >> 5;
#pragma unroll
    for (int j = 0; j < 4; j++)
      tile[ty + j * 8][tx] = in[(size_t)(r0 + ty + j * 8) * C + c0 + tx];
    __syncthreads();
#pragma unroll
    for (int j = 0; j < 4; j++)
      out[(size_t)(c0 + ty + j * 8) * R + r0 + tx] = (bf16)tile[tx][ty + j * 8];
  } else {
    int i = (blk - 5120) * 256 + tid;
    int s = i >> 5, d = i & 31;
    float inv = powf(10000.0f, -(float)d * (1.0f / 32.0f));
    float a = (float)s * inv;
    float sv, cv;
    sincosf(a, &sv, &cv);
    cosT[i] = cv; sinT[i] = sv;
  }
}

// ---------------- qkv GEMM: BM=128, BN=192, BK=64; counted-vmcnt dbuf (T4) ----------------
__global__ __launch_bounds__(512, 4) void gemm_qkv(const bf16* __restrict__ A,
                                                   const bf16* __restrict__ Bt,
                                                   bf16* __restrict__ Cb,
                                                   const float* __restrict__ cosT,
                                                   const float* __restrict__ sinT,
                                                   bf16* __restrict__ vt) {
  __shared__ __align__(16) unsigned char lds[81920];   // [2 buf][A 16K | B 24K]
  const int K = 1024;
  int tid = threadIdx.x, lane = tid & 63, w = tid >> 6;
  int bid = blockIdx.y * gridDim.x + blockIdx.x;       // nwg = 512
  int sw = (bid & 7) * 64 + (bid >> 3);
  int bx = sw & 15, by = sw >> 4;
  int m0 = by * 128, n0 = bx * 192;
  int rl = lane & 15, kg = lane >> 4;

  int r8 = tid >> 3;
  int cSw = ((tid & 7) ^ (r8 & 7)) * 16;               // pre-swizzled source chunk (involution)
  const char* Ab = (const char*)A;
  const char* Bb = (const char*)Bt;

#define QSTG(kt, bf)                                                                        \
  do {                                                                                      \
    char* base = (char*)lds + (bf) * 40960;                                                 \
    _Pragma("unroll")                                                                       \
    for (int s = 0; s < 2; s++)                                                             \
      gload_lds16(Ab + ((size_t)(m0 + s * 64 + r8) * K + (kt) * 64) * 2 + cSw,              \
                  base + s * 8192 + tid * 16);                                              \
    _Pragma("unroll")                                                                       \
    for (int s = 0; s < 3; s++)                                                             \
      gload_lds16(Bb + ((size_t)(n0 + s * 64 + r8) * K + (kt) * 64) * 2 + cSw,              \
                  base + 16384 + s * 8192 + tid * 16);                                      \
  } while (0)

  int ch0 = ((kg + 0) ^ (rl & 7)) * 16;
  int ch1 = ((kg + 4) ^ (rl & 7)) * 16;
  int aoff = (w * 16 + rl) * 128;

  f32x4 acc[12] = {};

  // prologue: tiles 0 and 1 in flight; wait tile 0 only (counted)
  QSTG(0, 0);
  QSTG(1, 1);
  asm volatile("s_waitcnt vmcnt(5)" ::: "memory");
  __builtin_amdgcn_s_barrier();

  for (int kt = 0; kt < 16; kt++) {
    int cur = kt & 1;
    const char* base = (const char*)lds + cur * 40960;
    bf16x8 a0 = *(const bf16x8*)(base + aoff + ch0);
    bf16x8 a1 = *(const bf16x8*)(base + aoff + ch1);
    __builtin_amdgcn_s_setprio(1);
#pragma unroll
    for (int br = 0; br < 12; br++) {
      int boff = 16384 + (br * 16 + rl) * 128;
      bf16x8 b0 = *(const bf16x8*)(base + boff + ch0);
      bf16x8 b1 = *(const bf16x8*)(base + boff + ch1);
      acc[br] = __builtin_amdgcn_mfma_f32_16x16x32_bf16(a0, b0, acc[br], 0, 0, 0);
      acc[br] = __builtin_amdgcn_mfma_f32_16x16x32_bf16(a1, b1, acc[br], 0, 0, 0);
    }
    __builtin_amdgcn_s_setprio(0);
    __builtin_amdgcn_s_barrier();                      // block-wide: reads of buf[cur] done
    if (kt + 2 < 16) QSTG(kt + 2, cur);                // refill buf[cur] with tile kt+2
    if (kt + 1 < 16) {
      if (kt + 2 < 16) asm volatile("s_waitcnt vmcnt(5)" ::: "memory");  // tile kt+1 landed
      else             asm volatile("s_waitcnt vmcnt(0)" ::: "memory");
      __builtin_amdgcn_s_barrier();                    // collective: tile kt+1 ready
    }
  }

  // ---- epilogue: per-64-col head group (n0 is 64-aligned) ----
  int rq = kg * 4;
#pragma unroll
  for (int hb = 0; hb < 3; hb++) {
    int g0 = n0 + hb * 64;
    if (g0 < 2048) {          // q/k: RoPE fused
#pragma unroll
      for (int j = 0; j < 2; j++) {
        int br = hb * 4 + j;
#pragma unroll
        for (int r = 0; r < 4; r++) {
          int row = m0 + w * 16 + rq + r;
          int srw = row & 2047;
          int d2 = j * 16 + rl;
          float c = cosT[srw * 32 + d2], sn = sinT[srw * 32 + d2];
          float x1 = acc[br][r], x2 = acc[br + 2][r];
          size_t o = (size_t)row * 3072 + g0 + d2;
          Cb[o]      = (bf16)(x1 * c - x2 * sn);
          Cb[o + 32] = (bf16)(x2 * c + x1 * sn);
        }
      }
    } else {                  // v: sigma-permuted V^T
      int posbase = ((rq & 4) << 1) | ((rq & 8) >> 1);
      int row0 = m0 + w * 16;
      int bb = row0 >> 11;
      int sbase = (row0 & 2047) + posbase;
#pragma unroll
      for (int j = 0; j < 4; j++) {
        int br = hb * 4 + j;
        int col = g0 + j * 16 + rl - 2048;
        bf16x4v pv;
        pv[0] = (bf16)acc[br][0]; pv[1] = (bf16)acc[br][1];
        pv[2] = (bf16)acc[br][2]; pv[3] = (bf16)acc[br][3];
        *(bf16x4v*)(vt + ((size_t)(bb * 1024 + col)) * 2048 + sbase) = pv;
      }
    }
  }
#undef QSTG
}

// ---------------- proj GEMM: BM=64, BN=128, BK=64; counted-vmcnt dbuf ----------------
__global__ __launch_bounds__(256) void gemm_proj(const bf16* __restrict__ A,
                                                 const bf16* __restrict__ Bt,
                                                 float* __restrict__ Cf,
                                                 const float* __restrict__ bias) {
  __shared__ __align__(16) unsigned char lds[49152];  // [2 buf][A 8K | B 16K]
  const int K = 1024, N = 1024;
  int tid = threadIdx.x;
  int lane = tid & 63, w = tid >> 6;
  int bid = blockIdx.y * gridDim.x + blockIdx.x;   // nwg = 512
  int sw = (bid & 7) * 64 + (bid >> 3);
  int bx = sw & 7, by = sw >> 3;
  int m0 = by * 64, n0 = bx * 128;
  int m_off = (w >> 1) * 32, n_off = (w & 1) * 64;
  int rl = lane & 15, kg = lane >> 4;
  f32x4 acc[2][4] = {};

  const char* Ab = (const char*)A;
  const char* Bb = (const char*)Bt;
  int r8 = tid >> 3;
  int cSw = ((tid & 7) ^ (r8 & 7)) * 16;

#define PSTG(kt, bf)                                                                     \
  do {                                                                                   \
    char* base = (char*)lds + (bf) * 24576;                                              \
    _Pragma("unroll")                                                                    \
    for (int s = 0; s < 2; s++)                                                          \
      gload_lds16(Ab + ((size_t)(m0 + s * 32 + r8) * K + (kt) * 64) * 2 + cSw,           \
                  base + s * 4096 + tid * 16);                                           \
    _Pragma("unroll")                                                                    \
    for (int s = 0; s < 4; s++)                                                          \
      gload_lds16(Bb + ((size_t)(n0 + s * 32 + r8) * K + (kt) * 64) * 2 + cSw,           \
                  base + 8192 + s * 4096 + tid * 16);                                    \
  } while (0)

  int ch0 = ((0 + kg) ^ (rl & 7)) * 16;
  int ch1 = ((4 + kg) ^ (rl & 7)) * 16;

  PSTG(0, 0);
  PSTG(1, 1);
  asm volatile("s_waitcnt vmcnt(6)" ::: "memory");
  __builtin_amdgcn_s_barrier();

  for (int kt = 0; kt < 16; kt++) {
    int cur = kt & 1;
    const char* base = (const char*)lds + cur * 24576;
    bf16x8 a[2][2], b[4][2];
#pragma unroll
    for (int i = 0; i < 2; i++) {
      int row = m_off + i * 16 + rl;
      a[i][0] = *(const bf16x8*)(base + row * 128 + ch0);
      a[i][1] = *(const bf16x8*)(base + row * 128 + ch1);
    }
#pragma unroll
    for (int j = 0; j < 4; j++) {
      int row = n_off + j * 16 + rl;
      b[j][0] = *(const bf16x8*)(base + 8192 + row * 128 + ch0);
      b[j][1] = *(const bf16x8*)(base + 8192 + row * 128 + ch1);
    }
    __builtin_amdgcn_s_setprio(1);
#pragma unroll
    for (int i = 0; i < 2; i++)
#pragma unroll
      for (int j = 0; j < 4; j++) {
        acc[i][j] = __builtin_amdgcn_mfma_f32_16x16x32_bf16(a[i][0], b[j][0], acc[i][j], 0, 0, 0);
        acc[i][j] = __builtin_amdgcn_mfma_f32_16x16x32_bf16(a[i][1], b[j][1], acc[i][j], 0, 0, 0);
      }
    __builtin_amdgcn_s_setprio(0);
    __builtin_amdgcn_s_barrier();                      // reads of buf[cur] done
    if (kt + 2 < 16) PSTG(kt + 2, cur);
    if (kt + 1 < 16) {
      if (kt + 2 < 16) asm volatile("s_waitcnt vmcnt(6)" ::: "memory");
      else             asm volatile("s_waitcnt vmcnt(0)" ::: "memory");
      __builtin_amdgcn_s_barrier();
    }
  }

  int rq = kg * 4;
  for (int i = 0; i < 2; i++)
    for (int j = 0; j < 4; j++) {
      int col = n0 + n_off + j * 16 + rl;
      float bv = bias[col];
      for (int r = 0; r < 4; r++) {
        int row = m0 + m_off + i * 16 + rq + r;
        Cf[(size_t)row * N + col] = acc[i][j][r] + bv;
      }
    }
#undef PSTG
}

// ---------------- flash attention: r16-exact (LPT, setprio, raw-exp P path) ----------------
__global__ __launch_bounds__(512, 4) void attn_kernel(const bf16* __restrict__ qkv,
                                                      const bf16* __restrict__ vt,
                                                      bf16* __restrict__ O) {
  __shared__ __align__(16) unsigned char Ks[2][16384];
  __shared__ __align__(16) unsigned char Vs[2][16384];
  int tid = threadIdx.x, lane = tid & 63, w = tid >> 6;
  int qw = w & 3, p = w >> 2;
  int bid = blockIdx.x;
  int xcd = bid & 7, slot = bid >> 3;
  int bh = xcd * 4 + (slot & 3);
  int u = slot >> 2;
  int qt = 15 - u;                         // LPT
  int b = bh >> 4, h = bh & 15;
  int q0w = qt * 128 + qw * 32;
  int l31 = lane & 31, hi = lane >> 5;
  const char* qb = (const char*)qkv;
  const char* vb = (const char*)vt;

  int kr0 = tid >> 3, kcs = (tid & 7) ^ (kr0 & 7);
  int vr0 = tid >> 4, vcs = (tid & 15) ^ (vr0 & 7);

#define STAGE(buf, kvbase)                                                                              \
  do {                                                                                                  \
    gload_lds16(qb + (((size_t)(b * 2048 + (kvbase) + kr0) * 3072) + 1024 + h * 64) * 2 + kcs * 16,     \
                (char*)Ks[buf] + tid * 16);                                                             \
    gload_lds16(qb + (((size_t)(b * 2048 + (kvbase) + kr0 + 64) * 3072) + 1024 + h * 64) * 2 + kcs * 16,\
                (char*)Ks[buf] + (tid + 512) * 16);                                                     \
    gload_lds16(vb + (((size_t)(bh * 64 + vr0) * 2048) + (kvbase)) * 2 + vcs * 16,                      \
                (char*)Vs[buf] + tid * 16);                                                             \
    gload_lds16(vb + (((size_t)(bh * 64 + vr0 + 32) * 2048) + (kvbase)) * 2 + vcs * 16,                 \
                (char*)Vs[buf] + (tid + 512) * 16);                                                     \
  } while (0)

  bf16x8 aq[4];
#pragma unroll
  for (int s = 0; s < 4; s++) {
    size_t row = (size_t)(b * 2048 + q0w + l31);
    bf16x8 v = *(const bf16x8*)(qb + (row * 3072 + h * 64 + s * 16 + hi * 8) * 2);
#pragma unroll
    for (int e = 0; e < 8; e++) v[e] = (bf16)((float)v[e] * 0.18033688f);
    aq[s] = v;
  }

  f32x16 o0 = {}, o1 = {};
  float mrun = -3e38f, lrun = 0.f;
  int npair = qt + 1;

  STAGE(0, 0);
  asm volatile("s_waitcnt vmcnt(0)" ::: "memory");
  __builtin_amdgcn_s_barrier();

  for (int i = 0; i < npair; i++) {
    int cur = i & 1;
    if (i + 1 < npair) STAGE(cur ^ 1, (i + 1) * 128);

    int kvw = i * 128 + p * 64;
    if (kvw <= q0w + 31) {
      bool diag = (kvw + 63 > q0w);

      f32x16 scr[2];
#pragma unroll
      for (int kf = 0; kf < 2; kf++)
#pragma unroll
        for (int r = 0; r < 16; r++) scr[kf][r] = 0.f;
      __builtin_amdgcn_s_setprio(1);
#pragma unroll
      for (int s = 0; s < 4; s++) {
#pragma unroll
        for (int kf = 0; kf < 2; kf++) {
          int row = p * 64 + kf * 32 + l31;
          int ch = (hi + 2 * s) ^ (row & 7);
          bf16x8 ak = *(const bf16x8*)(Ks[cur] + row * 128 + ch * 16);
          scr[kf] = __builtin_amdgcn_mfma_f32_32x32x16_bf16(ak, aq[s], scr[kf], 0, 0, 0);
        }
      }
      __builtin_amdgcn_s_setprio(0);

      int qg = q0w + l31;
      if (diag) {
#pragma unroll
        for (int kf = 0; kf < 2; kf++)
#pragma unroll
          for (int r = 0; r < 16; r++) {
            int k = kvw + kf * 32 + (r & 3) + 8 * (r >> 2) + 4 * hi;
            if (k > qg) scr[kf][r] = -3e38f;
          }
      }

      float mx = -3e38f;
#pragma unroll
      for (int kf = 0; kf < 2; kf++)
#pragma unroll
        for (int r = 0; r < 16; r++) mx = fmaxf(mx, scr[kf][r]);
      mx = fmaxf(mx, __shfl_xor(mx, 32));

      // T13 defer-max (state path libm exp2f)
      if (!__all(mx - mrun <= 11.5f)) {
        float mnew = fmaxf(mrun, mx);
        float corr = exp2f(mrun - mnew);
        mrun = mnew;
        lrun *= corr;
#pragma unroll
        for (int r = 0; r < 16; r++) {
          float cr = __shfl(corr, (r & 3) + 8 * (r >> 2) + 4 * hi);
          o0[r] *= cr; o1[r] *= cr;
        }
      }

      float rs = 0.f;
      unsigned D[2][8];
#pragma unroll
      for (int kf = 0; kf < 2; kf++)
#pragma unroll
        for (int j = 0; j < 8; j++) {
          float p0 = fast_exp2(scr[kf][2 * j] - mrun);
          float p1 = fast_exp2(scr[kf][2 * j + 1] - mrun);
          rs += p0 + p1;
          bf16x2 tp; tp[0] = (bf16)p0; tp[1] = (bf16)p1;
          D[kf][j] = __builtin_bit_cast(unsigned, tp);
        }
      rs += __shfl_xor(rs, 32);
      lrun += rs;

#pragma unroll
      for (int kf = 0; kf < 2; kf++) {
#pragma unroll
        for (int sg = 0; sg < 2; sg++) {
          union { unsigned u4[4]; bf16x8 v; } ap;
          ap.u4[0] = D[kf][4 * sg + 0];
          ap.u4[1] = D[kf][4 * sg + 1];
          ap.u4[2] = D[kf][4 * sg + 2];
          ap.u4[3] = D[kf][4 * sg + 3];
          __builtin_amdgcn_s_setprio(1);
#pragma unroll
          for (int nf = 0; nf < 2; nf++) {
            int row = nf * 32 + l31;
            int ch = ((p * 8) + (hi + 2 * sg + 4 * kf)) ^ (row & 7);
            bf16x8 bv = *(const bf16x8*)(Vs[cur] + row * 256 + ch * 16);
            if (nf == 0) o0 = __builtin_amdgcn_mfma_f32_32x32x16_bf16(ap.v, bv, o0, 0, 0, 0);
            else         o1 = __builtin_amdgcn_mfma_f32_32x32x16_bf16(ap.v, bv, o1, 0, 0, 0);
          }
          __builtin_amdgcn_s_setprio(0);
        }
      }
    }

    asm volatile("s_waitcnt vmcnt(0)" ::: "memory");
    __builtin_amdgcn_s_barrier();
  }

  float* mlb = (float*)Ks;
  if (hi == 0) {
    mlb[((qw * 2 + p) * 2 + 0) * 32 + l31] = mrun;
    mlb[((qw * 2 + p) * 2 + 1) * 32 + l31] = lrun;
  }
  __syncthreads();
  float m_o = mlb[((qw * 2 + (1 - p)) * 2 + 0) * 32 + l31];
  float l_o = mlb[((qw * 2 + (1 - p)) * 2 + 1) * 32 + l31];
  float Mm = fmaxf(mrun, m_o);
  float cs = exp2f(mrun - Mm);
  float L  = lrun * cs + l_o * exp2f(m_o - Mm);
  float* obuf = (float*)Vs;
  if (p == 1) {
#pragma unroll
    for (int r = 0; r < 16; r++) {
      int crow = (r & 3) + 8 * (r >> 2) + 4 * hi;
      float c = __shfl(cs, crow);
      obuf[qw * 2048 + r * 64 + lane]        = o0[r] * c;
      obuf[qw * 2048 + (r + 16) * 64 + lane] = o1[r] * c;
    }
  }
  __syncthreads();
  if (p == 0) {
    float linv = 1.0f / L;
#pragma unroll
    for (int r = 0; r < 16; r++) {
      int crow = (r & 3) + 8 * (r >> 2) + 4 * hi;
      float c  = __shfl(cs, crow);
      float li = __shfl(linv, crow);
      size_t row = (size_t)(b * 2048 + q0w + crow);
      float v0 = (o0[r] * c + obuf[qw * 2048 + r * 64 + lane]) * li;
      float v1 = (o1[r] * c + obuf[qw * 2048 + (r + 16) * 64 + lane]) * li;
      O[row * 1024 + h * 64 + l31]      = (bf16)v0;
      O[row * 1024 + h * 64 + 32 + l31] = (bf16)v1;
    }
  }
#undef STAGE
}

extern "C" void kernel_launch(void* const* d_in, const int* in_sizes, int n_in,
                              void* d_out, int out_size, void* d_ws, size_t ws_size,
                              hipStream_t stream) {
  const float* x      = (const float*)d_in[0];
  const float* w_qkv  = (const float*)d_in[1];
  const float* w_proj = (const float*)d_in[2];
  const float* b_proj = (const float*)d_in[3];

  char* ws = (char*)d_ws;
  size_t off = 0;
  bf16* xb     = (bf16*)(ws + off); off += (size_t)M_ * D_ * 2;
  bf16* wqkvT  = (bf16*)(ws + off); off += (size_t)N3_ * D_ * 2;
  bf16* wprojT = (bf16*)(ws + off); off += (size_t)D_ * D_ * 2;
  bf16* qkvb   = (bf16*)(ws + off); off += (size_t)M_ * N3_ * 2;
  bf16* ob     = (bf16*)(ws + off); off += (size_t)M_ * D_ * 2;
  bf16* vtb    = (bf16*)(ws + off); off += (size_t)M_ * D_ * 2;
  float* cosT  = (float*)(ws + off); off += (size_t)S_ * 32 * 4;
  float* sinT  = (float*)(ws + off); off += (size_t)S_ * 32 * 4;

  prep_kernel<<<5376, 256, 0, stream>>>(x, xb, w_qkv, wqkvT, w_proj, wprojT, cosT, sinT);
  gemm_qkv<<<dim3(16, 32), 512, 0, stream>>>(xb, wqkvT, qkvb, cosT, sinT, vtb);
  attn_kernel<<<512, 512, 0, stream>>>(qkvb, vtb, ob);
  gemm_proj<<<dim3(8, 64), 256, 0, stream>>>(ob, wprojT, (float*)d_out, b_proj);
}

// Round 23
// 91.921 us; speedup vs baseline: 1.1867x; 1.0045x over previous
//
#include <hip/hip_runtime.h>
#include <stdint.h>
#include <math.h>

#define B_   2
#define S_   2048
#define D_   1024
#define H_   16
#define HD_  64
#define M_   (B_*S_)     // 4096
#define N3_  (3*D_)      // 3072

typedef __bf16 bf16;
typedef __bf16 bf16x2 __attribute__((ext_vector_type(2)));
typedef __bf16 bf16x4v __attribute__((ext_vector_type(4)));
typedef __bf16 bf16x8 __attribute__((ext_vector_type(8)));
typedef float  f32x4 __attribute__((ext_vector_type(4)));
typedef float  f32x16 __attribute__((ext_vector_type(16)));

__device__ __forceinline__ void gload_lds16(const void* g, void* l) {
  __builtin_amdgcn_global_load_lds(
      (__attribute__((address_space(1))) const unsigned int*)g,
      (__attribute__((address_space(3))) unsigned int*)l, 16, 0, 0);
}

// raw v_exp_f32 (2^x) via compiler builtin — P path only (proven r16)
__device__ __forceinline__ float fast_exp2(float x) {
  return __builtin_amdgcn_exp2f(x);
}

// ---------------- fused pre-pass: conv + both weight transposes + rope table ----------------
__global__ __launch_bounds__(256) void prep_kernel(const float* __restrict__ x, bf16* __restrict__ xb,
                                                   const float* __restrict__ w_qkv, bf16* __restrict__ wqkvT,
                                                   const float* __restrict__ w_proj, bf16* __restrict__ wprojT,
                                                   float* __restrict__ cosT, float* __restrict__ sinT) {
  __shared__ float tile[32][33];
  int blk = blockIdx.x, tid = threadIdx.x;
  if (blk < 1024) {
#pragma unroll
    for (int it = 0; it < 4; it++) {
      int i = (blk * 4 + it) * 256 + tid;
      float4 v = ((const float4*)x)[i];
      bf16x4v o;
      o[0] = (bf16)v.x; o[1] = (bf16)v.y; o[2] = (bf16)v.z; o[3] = (bf16)v.w;
      *(bf16x4v*)(xb + (size_t)i * 4) = o;
    }
  } else if (blk < 5120) {
    const float* in; bf16* out; int R, C, tb;
    if (blk < 4096) { in = w_qkv;  out = wqkvT;  R = 1024; C = 3072; tb = blk - 1024; }
    else            { in = w_proj; out = wprojT; R = 1024; C = 1024; tb = blk - 4096; }
    int nbx = C >> 5;
    int bx = tb % nbx, by = tb / nbx;
    int c0 = bx * 32, r0 = by * 32;
    int tx = tid & 31, ty = tid >> 5;
#pragma unroll
    for (int j = 0; j < 4; j++)
      tile[ty + j * 8][tx] = in[(size_t)(r0 + ty + j * 8) * C + c0 + tx];
    __syncthreads();
#pragma unroll
    for (int j = 0; j < 4; j++)
      out[(size_t)(c0 + ty + j * 8) * R + r0 + tx] = (bf16)tile[tx][ty + j * 8];
  } else {
    int i = (blk - 5120) * 256 + tid;
    int s = i >> 5, d = i & 31;
    float inv = powf(10000.0f, -(float)d * (1.0f / 32.0f));
    float a = (float)s * inv;
    float sv, cv;
    sincosf(a, &sv, &cv);
    cosT[i] = cv; sinT[i] = sv;
  }
}

// ---------------- qkv GEMM: BM=128, BN=192, BK=64; counted-vmcnt dbuf (T4) ----------------
__global__ __launch_bounds__(512, 4) void gemm_qkv(const bf16* __restrict__ A,
                                                   const bf16* __restrict__ Bt,
                                                   bf16* __restrict__ Cb,
                                                   const float* __restrict__ cosT,
                                                   const float* __restrict__ sinT,
                                                   bf16* __restrict__ vt) {
  __shared__ __align__(16) unsigned char lds[81920];   // [2 buf][A 16K | B 24K]
  const int K = 1024;
  int tid = threadIdx.x, lane = tid & 63, w = tid >> 6;
  int bid = blockIdx.y * gridDim.x + blockIdx.x;       // nwg = 512
  int sw = (bid & 7) * 64 + (bid >> 3);
  int bx = sw & 15, by = sw >> 4;
  int m0 = by * 128, n0 = bx * 192;
  int rl = lane & 15, kg = lane >> 4;

  int r8 = tid >> 3;
  int cSw = ((tid & 7) ^ (r8 & 7)) * 16;               // pre-swizzled source chunk (involution)
  const char* Ab = (const char*)A;
  const char* Bb = (const char*)Bt;

#define QSTG(kt, bf)                                                                        \
  do {                                                                                      \
    char* base = (char*)lds + (bf) * 40960;                                                 \
    _Pragma("unroll")                                                                       \
    for (int s = 0; s < 2; s++)                                                             \
      gload_lds16(Ab + ((size_t)(m0 + s * 64 + r8) * K + (kt) * 64) * 2 + cSw,              \
                  base + s * 8192 + tid * 16);                                              \
    _Pragma("unroll")                                                                       \
    for (int s = 0; s < 3; s++)                                                             \
      gload_lds16(Bb + ((size_t)(n0 + s * 64 + r8) * K + (kt) * 64) * 2 + cSw,              \
                  base + 16384 + s * 8192 + tid * 16);                                      \
  } while (0)

  int ch0 = ((kg + 0) ^ (rl & 7)) * 16;
  int ch1 = ((kg + 4) ^ (rl & 7)) * 16;
  int aoff = (w * 16 + rl) * 128;

  f32x4 acc[12] = {};

  QSTG(0, 0);
  QSTG(1, 1);
  asm volatile("s_waitcnt vmcnt(5)" ::: "memory");
  __builtin_amdgcn_s_barrier();

  for (int kt = 0; kt < 16; kt++) {
    int cur = kt & 1;
    const char* base = (const char*)lds + cur * 40960;
    bf16x8 a0 = *(const bf16x8*)(base + aoff + ch0);
    bf16x8 a1 = *(const bf16x8*)(base + aoff + ch1);
    __builtin_amdgcn_s_setprio(1);
#pragma unroll
    for (int br = 0; br < 12; br++) {
      int boff = 16384 + (br * 16 + rl) * 128;
      bf16x8 b0 = *(const bf16x8*)(base + boff + ch0);
      bf16x8 b1 = *(const bf16x8*)(base + boff + ch1);
      acc[br] = __builtin_amdgcn_mfma_f32_16x16x32_bf16(a0, b0, acc[br], 0, 0, 0);
      acc[br] = __builtin_amdgcn_mfma_f32_16x16x32_bf16(a1, b1, acc[br], 0, 0, 0);
    }
    __builtin_amdgcn_s_setprio(0);
    __builtin_amdgcn_s_barrier();                      // reads of buf[cur] done
    if (kt + 2 < 16) QSTG(kt + 2, cur);
    if (kt + 1 < 16) {
      if (kt + 2 < 16) asm volatile("s_waitcnt vmcnt(5)" ::: "memory");
      else             asm volatile("s_waitcnt vmcnt(0)" ::: "memory");
      __builtin_amdgcn_s_barrier();
    }
  }

  // ---- epilogue: per-64-col head group (n0 is 64-aligned) ----
  int rq = kg * 4;
#pragma unroll
  for (int hb = 0; hb < 3; hb++) {
    int g0 = n0 + hb * 64;
    if (g0 < 2048) {          // q/k: RoPE fused
#pragma unroll
      for (int j = 0; j < 2; j++) {
        int br = hb * 4 + j;
#pragma unroll
        for (int r = 0; r < 4; r++) {
          int row = m0 + w * 16 + rq + r;
          int srw = row & 2047;
          int d2 = j * 16 + rl;
          float c = cosT[srw * 32 + d2], sn = sinT[srw * 32 + d2];
          float x1 = acc[br][r], x2 = acc[br + 2][r];
          size_t o = (size_t)row * 3072 + g0 + d2;
          Cb[o]      = (bf16)(x1 * c - x2 * sn);
          Cb[o + 32] = (bf16)(x2 * c + x1 * sn);
        }
      }
    } else {                  // v: sigma-permuted V^T
      int posbase = ((rq & 4) << 1) | ((rq & 8) >> 1);
      int row0 = m0 + w * 16;
      int bb = row0 >> 11;
      int sbase = (row0 & 2047) + posbase;
#pragma unroll
      for (int j = 0; j < 4; j++) {
        int br = hb * 4 + j;
        int col = g0 + j * 16 + rl - 2048;
        bf16x4v pv;
        pv[0] = (bf16)acc[br][0]; pv[1] = (bf16)acc[br][1];
        pv[2] = (bf16)acc[br][2]; pv[3] = (bf16)acc[br][3];
        *(bf16x4v*)(vt + ((size_t)(bb * 1024 + col)) * 2048 + sbase) = pv;
      }
    }
  }
#undef QSTG
}

// ---------------- proj GEMM: BM=64, BN=128, BK=64; counted-vmcnt dbuf ----------------
__global__ __launch_bounds__(256) void gemm_proj(const bf16* __restrict__ A,
                                                 const bf16* __restrict__ Bt,
                                                 float* __restrict__ Cf,
                                                 const float* __restrict__ bias) {
  __shared__ __align__(16) unsigned char lds[49152];  // [2 buf][A 8K | B 16K]
  const int K = 1024, N = 1024;
  int tid = threadIdx.x;
  int lane = tid & 63, w = tid >> 6;
  int bid = blockIdx.y * gridDim.x + blockIdx.x;   // nwg = 512
  int sw = (bid & 7) * 64 + (bid >> 3);
  int bx = sw & 7, by = sw >> 3;
  int m0 = by * 64, n0 = bx * 128;
  int m_off = (w >> 1) * 32, n_off = (w & 1) * 64;
  int rl = lane & 15, kg = lane >> 4;
  f32x4 acc[2][4] = {};

  const char* Ab = (const char*)A;
  const char* Bb = (const char*)Bt;
  int r8 = tid >> 3;
  int cSw = ((tid & 7) ^ (r8 & 7)) * 16;

#define PSTG(kt, bf)                                                                     \
  do {                                                                                   \
    char* base = (char*)lds + (bf) * 24576;                                              \
    _Pragma("unroll")                                                                    \
    for (int s = 0; s < 2; s++)                                                          \
      gload_lds16(Ab + ((size_t)(m0 + s * 32 + r8) * K + (kt) * 64) * 2 + cSw,           \
                  base + s * 4096 + tid * 16);                                           \
    _Pragma("unroll")                                                                    \
    for (int s = 0; s < 4; s++)                                                          \
      gload_lds16(Bb + ((size_t)(n0 + s * 32 + r8) * K + (kt) * 64) * 2 + cSw,           \
                  base + 8192 + s * 4096 + tid * 16);                                    \
  } while (0)

  int ch0 = ((0 + kg) ^ (rl & 7)) * 16;
  int ch1 = ((4 + kg) ^ (rl & 7)) * 16;

  PSTG(0, 0);
  PSTG(1, 1);
  asm volatile("s_waitcnt vmcnt(6)" ::: "memory");
  __builtin_amdgcn_s_barrier();

  for (int kt = 0; kt < 16; kt++) {
    int cur = kt & 1;
    const char* base = (const char*)lds + cur * 24576;
    bf16x8 a[2][2], b[4][2];
#pragma unroll
    for (int i = 0; i < 2; i++) {
      int row = m_off + i * 16 + rl;
      a[i][0] = *(const bf16x8*)(base + row * 128 + ch0);
      a[i][1] = *(const bf16x8*)(base + row * 128 + ch1);
    }
#pragma unroll
    for (int j = 0; j < 4; j++) {
      int row = n_off + j * 16 + rl;
      b[j][0] = *(const bf16x8*)(base + 8192 + row * 128 + ch0);
      b[j][1] = *(const bf16x8*)(base + 8192 + row * 128 + ch1);
    }
    __builtin_amdgcn_s_setprio(1);
#pragma unroll
    for (int i = 0; i < 2; i++)
#pragma unroll
      for (int j = 0; j < 4; j++) {
        acc[i][j] = __builtin_amdgcn_mfma_f32_16x16x32_bf16(a[i][0], b[j][0], acc[i][j], 0, 0, 0);
        acc[i][j] = __builtin_amdgcn_mfma_f32_16x16x32_bf16(a[i][1], b[j][1], acc[i][j], 0, 0, 0);
      }
    __builtin_amdgcn_s_setprio(0);
    __builtin_amdgcn_s_barrier();
    if (kt + 2 < 16) PSTG(kt + 2, cur);
    if (kt + 1 < 16) {
      if (kt + 2 < 16) asm volatile("s_waitcnt vmcnt(6)" ::: "memory");
      else             asm volatile("s_waitcnt vmcnt(0)" ::: "memory");
      __builtin_amdgcn_s_barrier();
    }
  }

  int rq = kg * 4;
  for (int i = 0; i < 2; i++)
    for (int j = 0; j < 4; j++) {
      int col = n0 + n_off + j * 16 + rl;
      float bv = bias[col];
      for (int r = 0; r < 4; r++) {
        int row = m0 + m_off + i * 16 + rq + r;
        Cf[(size_t)row * N + col] = acc[i][j][r] + bv;
      }
    }
#undef PSTG
}

// ---------------- flash attention: r16 body + 2-deep counted-vmcnt staging (T4) ----------------
__global__ __launch_bounds__(512, 4) void attn_kernel(const bf16* __restrict__ qkv,
                                                      const bf16* __restrict__ vt,
                                                      bf16* __restrict__ O) {
  __shared__ __align__(16) unsigned char Ks[2][16384];
  __shared__ __align__(16) unsigned char Vs[2][16384];
  int tid = threadIdx.x, lane = tid & 63, w = tid >> 6;
  int qw = w & 3, p = w >> 2;
  int bid = blockIdx.x;
  int xcd = bid & 7, slot = bid >> 3;
  int bh = xcd * 4 + (slot & 3);
  int u = slot >> 2;
  int qt = 15 - u;                         // LPT
  int b = bh >> 4, h = bh & 15;
  int q0w = qt * 128 + qw * 32;
  int l31 = lane & 31, hi = lane >> 5;
  const char* qb = (const char*)qkv;
  const char* vb = (const char*)vt;

  int kr0 = tid >> 3, kcs = (tid & 7) ^ (kr0 & 7);
  int vr0 = tid >> 4, vcs = (tid & 15) ^ (vr0 & 7);

#define STAGE(buf, kvbase)                                                                              \
  do {                                                                                                  \
    gload_lds16(qb + (((size_t)(b * 2048 + (kvbase) + kr0) * 3072) + 1024 + h * 64) * 2 + kcs * 16,     \
                (char*)Ks[buf] + tid * 16);                                                             \
    gload_lds16(qb + (((size_t)(b * 2048 + (kvbase) + kr0 + 64) * 3072) + 1024 + h * 64) * 2 + kcs * 16,\
                (char*)Ks[buf] + (tid + 512) * 16);                                                     \
    gload_lds16(vb + (((size_t)(bh * 64 + vr0) * 2048) + (kvbase)) * 2 + vcs * 16,                      \
                (char*)Vs[buf] + tid * 16);                                                             \
    gload_lds16(vb + (((size_t)(bh * 64 + vr0 + 32) * 2048) + (kvbase)) * 2 + vcs * 16,                 \
                (char*)Vs[buf] + (tid + 512) * 16);                                                     \
  } while (0)

  bf16x8 aq[4];
#pragma unroll
  for (int s = 0; s < 4; s++) {
    size_t row = (size_t)(b * 2048 + q0w + l31);
    bf16x8 v = *(const bf16x8*)(qb + (row * 3072 + h * 64 + s * 16 + hi * 8) * 2);
#pragma unroll
    for (int e = 0; e < 8; e++) v[e] = (bf16)((float)v[e] * 0.18033688f);
    aq[s] = v;
  }

  f32x16 o0 = {}, o1 = {};
  float mrun = -3e38f, lrun = 0.f;
  int npair = qt + 1;

  // prologue: tiles 0 and 1 in flight; wait tile 0 only (counted)
  STAGE(0, 0);
  if (npair > 1) {
    STAGE(1, 128);
    asm volatile("s_waitcnt vmcnt(4)" ::: "memory");
  } else {
    asm volatile("s_waitcnt vmcnt(0)" ::: "memory");
  }
  __builtin_amdgcn_s_barrier();

  for (int i = 0; i < npair; i++) {
    int cur = i & 1;
    int kvw = i * 128 + p * 64;
    if (kvw <= q0w + 31) {
      bool diag = (kvw + 63 > q0w);

      f32x16 scr[2];
#pragma unroll
      for (int kf = 0; kf < 2; kf++)
#pragma unroll
        for (int r = 0; r < 16; r++) scr[kf][r] = 0.f;
      __builtin_amdgcn_s_setprio(1);
#pragma unroll
      for (int s = 0; s < 4; s++) {
#pragma unroll
        for (int kf = 0; kf < 2; kf++) {
          int row = p * 64 + kf * 32 + l31;
          int ch = (hi + 2 * s) ^ (row & 7);
          bf16x8 ak = *(const bf16x8*)(Ks[cur] + row * 128 + ch * 16);
          scr[kf] = __builtin_amdgcn_mfma_f32_32x32x16_bf16(ak, aq[s], scr[kf], 0, 0, 0);
        }
      }
      __builtin_amdgcn_s_setprio(0);

      int qg = q0w + l31;
      if (diag) {
#pragma unroll
        for (int kf = 0; kf < 2; kf++)
#pragma unroll
          for (int r = 0; r < 16; r++) {
            int k = kvw + kf * 32 + (r & 3) + 8 * (r >> 2) + 4 * hi;
            if (k > qg) scr[kf][r] = -3e38f;
          }
      }

      float mx = -3e38f;
#pragma unroll
      for (int kf = 0; kf < 2; kf++)
#pragma unroll
        for (int r = 0; r < 16; r++) mx = fmaxf(mx, scr[kf][r]);
      mx = fmaxf(mx, __shfl_xor(mx, 32));

      // T13 defer-max (state path libm exp2f)
      if (!__all(mx - mrun <= 11.5f)) {
        float mnew = fmaxf(mrun, mx);
        float corr = exp2f(mrun - mnew);
        mrun = mnew;
        lrun *= corr;
#pragma unroll
        for (int r = 0; r < 16; r++) {
          float cr = __shfl(corr, (r & 3) + 8 * (r >> 2) + 4 * hi);
          o0[r] *= cr; o1[r] *= cr;
        }
      }

      float rs = 0.f;
      unsigned D[2][8];
#pragma unroll
      for (int kf = 0; kf < 2; kf++)
#pragma unroll
        for (int j = 0; j < 8; j++) {
          float p0 = fast_exp2(scr[kf][2 * j] - mrun);
          float p1 = fast_exp2(scr[kf][2 * j + 1] - mrun);
          rs += p0 + p1;
          bf16x2 tp; tp[0] = (bf16)p0; tp[1] = (bf16)p1;
          D[kf][j] = __builtin_bit_cast(unsigned, tp);
        }
      rs += __shfl_xor(rs, 32);
      lrun += rs;

#pragma unroll
      for (int kf = 0; kf < 2; kf++) {
#pragma unroll
        for (int sg = 0; sg < 2; sg++) {
          union { unsigned u4[4]; bf16x8 v; } ap;
          ap.u4[0] = D[kf][4 * sg + 0];
          ap.u4[1] = D[kf][4 * sg + 1];
          ap.u4[2] = D[kf][4 * sg + 2];
          ap.u4[3] = D[kf][4 * sg + 3];
          __builtin_amdgcn_s_setprio(1);
#pragma unroll
          for (int nf = 0; nf < 2; nf++) {
            int row = nf * 32 + l31;
            int ch = ((p * 8) + (hi + 2 * sg + 4 * kf)) ^ (row & 7);
            bf16x8 bv = *(const bf16x8*)(Vs[cur] + row * 256 + ch * 16);
            if (nf == 0) o0 = __builtin_amdgcn_mfma_f32_32x32x16_bf16(ap.v, bv, o0, 0, 0, 0);
            else         o1 = __builtin_amdgcn_mfma_f32_32x32x16_bf16(ap.v, bv, o1, 0, 0, 0);
          }
          __builtin_amdgcn_s_setprio(0);
        }
      }
    }

    __builtin_amdgcn_s_barrier();                      // reads of buf[cur] done
    if (i + 2 < npair) STAGE(cur, (i + 2) * 128);      // refill freed buffer
    if (i + 1 < npair) {
      if (i + 2 < npair) asm volatile("s_waitcnt vmcnt(4)" ::: "memory");
      else               asm volatile("s_waitcnt vmcnt(0)" ::: "memory");
      __builtin_amdgcn_s_barrier();                    // tile i+1 ready
    }
  }

  float* mlb = (float*)Ks;
  if (hi == 0) {
    mlb[((qw * 2 + p) * 2 + 0) * 32 + l31] = mrun;
    mlb[((qw * 2 + p) * 2 + 1) * 32 + l31] = lrun;
  }
  __syncthreads();
  float m_o = mlb[((qw * 2 + (1 - p)) * 2 + 0) * 32 + l31];
  float l_o = mlb[((qw * 2 + (1 - p)) * 2 + 1) * 32 + l31];
  float Mm = fmaxf(mrun, m_o);
  float cs = exp2f(mrun - Mm);
  float L  = lrun * cs + l_o * exp2f(m_o - Mm);
  float* obuf = (float*)Vs;
  if (p == 1) {
#pragma unroll
    for (int r = 0; r < 16; r++) {
      int crow = (r & 3) + 8 * (r >> 2) + 4 * hi;
      float c = __shfl(cs, crow);
      obuf[qw * 2048 + r * 64 + lane]        = o0[r] * c;
      obuf[qw * 2048 + (r + 16) * 64 + lane] = o1[r] * c;
    }
  }
  __syncthreads();
  if (p == 0) {
    float linv = 1.0f / L;
#pragma unroll
    for (int r = 0; r < 16; r++) {
      int crow = (r & 3) + 8 * (r >> 2) + 4 * hi;
      float c  = __shfl(cs, crow);
      float li = __shfl(linv, crow);
      size_t row = (size_t)(b * 2048 + q0w + crow);
      float v0 = (o0[r] * c + obuf[qw * 2048 + r * 64 + lane]) * li;
      float v1 = (o1[r] * c + obuf[qw * 2048 + (r + 16) * 64 + lane]) * li;
      O[row * 1024 + h * 64 + l31]      = (bf16)v0;
      O[row * 1024 + h * 64 + 32 + l31] = (bf16)v1;
    }
  }
#undef STAGE
}

extern "C" void kernel_launch(void* const* d_in, const int* in_sizes, int n_in,
                              void* d_out, int out_size, void* d_ws, size_t ws_size,
                              hipStream_t stream) {
  const float* x      = (const float*)d_in[0];
  const float* w_qkv  = (const float*)d_in[1];
  const float* w_proj = (const float*)d_in[2];
  const float* b_proj = (const float*)d_in[3];

  char* ws = (char*)d_ws;
  size_t off = 0;
  bf16* xb     = (bf16*)(ws + off); off += (size_t)M_ * D_ * 2;
  bf16* wqkvT  = (bf16*)(ws + off); off += (size_t)N3_ * D_ * 2;
  bf16* wprojT = (bf16*)(ws + off); off += (size_t)D_ * D_ * 2;
  bf16* qkvb   = (bf16*)(ws + off); off += (size_t)M_ * N3_ * 2;
  bf16* ob     = (bf16*)(ws + off); off += (size_t)M_ * D_ * 2;
  bf16* vtb    = (bf16*)(ws + off); off += (size_t)M_ * D_ * 2;
  float* cosT  = (float*)(ws + off); off += (size_t)S_ * 32 * 4;
  float* sinT  = (float*)(ws + off); off += (size_t)S_ * 32 * 4;

  prep_kernel<<<5376, 256, 0, stream>>>(x, xb, w_qkv, wqkvT, w_proj, wprojT, cosT, sinT);
  gemm_qkv<<<dim3(16, 32), 512, 0, stream>>>(xb, wqkvT, qkvb, cosT, sinT, vtb);
  attn_kernel<<<512, 512, 0, stream>>>(qkvb, vtb, ob);
  gemm_proj<<<dim3(8, 64), 256, 0, stream>>>(ob, wprojT, (float*)d_out, b_proj);
}